// Round 10
// baseline (381.037 us; speedup 1.0000x reference)
//
#include <hip/hip_runtime.h>
#include <hip/hip_bf16.h>

// B=16, SEQ=512, NF=32, E=128, HID=512, PRED=96, N_FFT=64, HOP=32, TOPM=32
// W=17, F=33, LAM=0.01
#define LAM 0.01f

typedef __attribute__((ext_vector_type(8))) short v8s;
typedef __attribute__((ext_vector_type(4))) float v4f;

static __device__ __forceinline__ unsigned short f2bf(float f) {
    union { float f; unsigned int u; } v; v.f = f;
    unsigned int u = v.u;
    u += 0x7fffu + ((u >> 16) & 1u);   // RNE
    return (unsigned short)(u >> 16);
}
static __device__ __forceinline__ float bf2f(unsigned short h) {
    union { unsigned int u; float f; } c; c.u = ((unsigned int)h) << 16;
    return c.f;
}
// packed 2xf32 -> 2xbf16 (v_cvt_pk_bf16_f32 on gfx950); lo=a, hi=b
static __device__ __forceinline__ unsigned int pkbf(float a, float b) {
    union { __hip_bfloat162 h; unsigned int u; } c;
    c.h = __float22bfloat162_rn(float2{a, b});
    return c.u;
}

// async global->LDS DMA, 16 B/lane; lds base wave-uniform, lane i -> base+16i
static __device__ __forceinline__ void async16(const void* g, void* l) {
    __builtin_amdgcn_global_load_lds(
        (const __attribute__((address_space(1))) unsigned int*)g,
        (__attribute__((address_space(3))) unsigned int*)l, 16, 0, 0);
}

// Workspace layout (bytes)
#define OFF_COEF 0ull
#define OFF_V    69632ull
#define OFF_BINS 2297856ull
#define OFF_AIMG 3411968ull                     // 512*65536 bf16 swizzled = 67,108,864
#define OFF_W1P  70520832ull                    // 65536*512 bf16 swizzled = 67,108,864
#define OFF_HP   137629696ull                   // KS*512*512*2 (bf16 partials)

// ---------------------------------------------------------------------------
// Kernel PRE (flat 1D grid, role by block index). R10: DISPATCH-RATE theory —
// three different cvt inner loops (R6/R8/R9) all ran ~80us at 9284 blocks
// (116 blocks/us = CP dispatch ceiling; CUs starved at 19% occupancy).
// Cut grid 9284 -> 1604:
//  bid <   68  : coef (unchanged).
//  bid <  580  : stft, R0 single-block-per-bn form (512 blocks).
//  else        : cvt, 8 kb-tiles per block (1024 blocks).
// ---------------------------------------------------------------------------
__global__ __launch_bounds__(256) void pre_kernel(
    const float* __restrict__ w1, unsigned short* __restrict__ w1p,
    const float* __restrict__ emb,
    const float* __restrict__ Wr, const float* __restrict__ Wi,
    const float* __restrict__ Wrl, const float* __restrict__ Wil,
    const float* __restrict__ Wrr, const float* __restrict__ Wir,
    const float* __restrict__ br, const float* __restrict__ bi,
    float* __restrict__ coef,
    const float* __restrict__ x, float2* __restrict__ V, int* __restrict__ bins)
{
    __shared__ __align__(16) float smem[2452];   // 9.8 KB, stft branch

    const int tid = threadIdx.x;
    const int bid = blockIdx.x;

    if (bid < 68) {
        // ---- coef ----
        const int pair = bid * 2 + (tid >> 7);   // 0..135
        const int w = pair >> 3, j = pair & 7, e = tid & 127;
        float out;
        if (j < 6) {
            const float* Wj;
            switch (j) {
                case 0: Wj = Wr; break; case 1: Wj = Wi; break;
                case 2: Wj = Wrl; break; case 3: Wj = Wil; break;
                case 4: Wj = Wrr; break; default: Wj = Wir; break;
            }
            const float* p = Wj + (size_t)w * 16384 + e;
            float acc = 0.f;
            #pragma unroll 8
            for (int ep = 0; ep < 128; ++ep) acc = fmaf(emb[ep], p[ep * 128], acc);
            out = acc;
        } else if (j == 6) {
            out = br[w * 128 + e] - LAM;
        } else {
            out = bi[w * 128 + e] - LAM;
        }
        coef[((size_t)(w * 128 + e)) * 8 + j] = out;
        return;
    }

    if (bid < 580) {
        // ---- stft (R0 form: all 17 windows per bn block) ----
        float* sigL  = smem;                     // 576 floats
        float* winT  = smem + 576;               // 64
        float2* tw   = (float2*)(smem + 640);    // 64 float2
        float2* Sbuf = (float2*)(smem + 768);    // 561 float2
        float* absb  = smem + 1890;              // 561

        const int blk = bid - 68;
        const int b = blk >> 5, n = blk & 31;
        const float C64 = 0.09817477042468103f; // 2*pi/64

        if (tid < 64) {
            float ang = (float)tid * C64;
            winT[tid] = 0.5f - 0.5f * cosf(ang);
            tw[tid] = make_float2(cosf(ang), sinf(ang));   // libm: tie safety
        }
        for (int l = tid; l < 576; l += 256) {
            int t = (l < 32) ? (32 - l) : ((l < 544) ? (l - 32) : (1054 - l)); // reflect
            sigL[l] = x[(size_t)b * 16384 + t * 32 + n];
        }
        __syncthreads();

        for (int task = tid; task < 561; task += 256) {
            int wl = task / 33, f = task - wl * 33;
            float sr = 0.f, si = 0.f;
            int base = wl * 32;
            for (int t = 0; t < 64; ++t) {
                float sw = sigL[base + t] * winT[t];
                float2 cs = tw[(f * t) & 63];
                sr = fmaf(sw, cs.x, sr);
                si = fmaf(sw, -cs.y, si);
            }
            Sbuf[task] = make_float2(sr, si);
            absb[task] = sqrtf(fmaf(sr, sr, si * si));
        }
        __syncthreads();

        for (int task = tid; task < 561; task += 256) {
            int wl = task / 33, f = task - wl * 33;
            float a = absb[task];
            int base = wl * 33, rank = 0;
            for (int j = 0; j < 33; ++j) {
                float aj = absb[base + j];
                rank += (aj > a) || (aj == a && j < f);   // stable
            }
            if (rank < 32) {
                size_t o = ((size_t)blk * 17 + wl) * 32 + rank;
                V[o] = Sbuf[task];
                bins[o] = f;
            }
        }
        return;
    }

    // ---- cvt (LDS-free, 8 kb-tiles per block): cb = bid-580 in [0,1024) ----
    const int cb = bid - 580;
    const int nt = cb >> 8;                  // 0..3
    const int kbb = (cb & 255) * 8;          // base kb tile
    // per-thread chunk geometry (constant across tiles)
    const int np0 = tid >> 2, cs0 = tid & 3;
    const int clog0 = cs0 ^ ((np0 >> 2) & 3);
    const int np1 = (tid + 256) >> 2, cs1 = (tid + 256) & 3;
    const int clog1 = cs1 ^ ((np1 >> 2) & 3);

    #pragma unroll 2
    for (int t8 = 0; t8 < 8; ++t8) {
        const int kb = kbb + t8;
        const float* wsrc = w1 + (size_t)kb * 32 * 512 + nt * 128;
        unsigned short* dst = w1p + ((size_t)nt * 2048 + kb) * 4096;

        float v0[8], v1[8];
        const float* c0 = wsrc + (size_t)(clog0 * 8) * 512 + np0;
        const float* c1 = wsrc + (size_t)(clog1 * 8) * 512 + np1;
        #pragma unroll
        for (int j = 0; j < 8; ++j) v0[j] = c0[(size_t)j * 512];
        #pragma unroll
        for (int j = 0; j < 8; ++j) v1[j] = c1[(size_t)j * 512];

        unsigned int pk[4];
        #pragma unroll
        for (int j2 = 0; j2 < 4; ++j2) pk[j2] = pkbf(v0[j2 * 2], v0[j2 * 2 + 1]);
        *(uint4*)&dst[tid * 8] = make_uint4(pk[0], pk[1], pk[2], pk[3]);
        #pragma unroll
        for (int j2 = 0; j2 < 4; ++j2) pk[j2] = pkbf(v1[j2 * 2], v1[j2 * 2 + 1]);
        *(uint4*)&dst[(tid + 256) * 8] = make_uint4(pk[0], pk[1], pk[2], pk[3]);
    }
}

// ---------------------------------------------------------------------------
// Kernel C: mid — verbatim R0 structure (best verified).
// Yt AND M1t double-buffered -> exactly ONE barrier per w-iteration.
// Zero-halo V table Vs2[19][32]. Per-(b,n) inputs in LDS; MFMA 64x128;
// register OLA; bf16 swizzled A-image write. grid 512, 256 thr.
// ---------------------------------------------------------------------------
#define MID_ROLL(J0, J1, J2, J3)                                                \
    {                                                                           \
        _Pragma("unroll") for (int e2 = 0; e2 < 2; ++e2)                        \
        _Pragma("unroll") for (int i = 0; i < 4; ++i) {                         \
            roll[e2][J0][i] = fmaf(acc[0][e2][i], win16[0][i], roll[e2][J0][i]);\
            roll[e2][J1][i] = fmaf(acc[1][e2][i], win16[1][i], roll[e2][J1][i]);\
            roll[e2][J2][i] = fmaf(acc[2][e2][i], win16[2][i], roll[e2][J2][i]);\
            roll[e2][J3][i] = fmaf(acc[3][e2][i], win16[3][i], roll[e2][J3][i]);\
        }                                                                       \
    }

#define MID_FLUSH(JJA, JJB)                                                     \
    {                                                                           \
        _Pragma("unroll") for (int i = 0; i < 4; ++i) {                         \
            int tp = 32 * (w - 1) + q * 4 + i;                                  \
            float xb = xs[tp];                                                  \
            _Pragma("unroll") for (int e2 = 0; e2 < 2; ++e2) {                  \
                float val = fmaf(roll[e2][JJA][i], renv[0][i], xb * emb2[e2]);  \
                Aimg[cbase[e2] + (size_t)tp * 16384] = f2bf(val);               \
                roll[e2][JJA][i] = 0.f;                                         \
            }                                                                   \
            int tp2 = tp + 16;                                                  \
            float xb2 = xs[tp2];                                                \
            _Pragma("unroll") for (int e2 = 0; e2 < 2; ++e2) {                  \
                float val = fmaf(roll[e2][JJB][i], renv[1][i], xb2 * emb2[e2]); \
                Aimg[cbase[e2] + (size_t)tp2 * 16384] = f2bf(val);              \
                roll[e2][JJB][i] = 0.f;                                         \
            }                                                                   \
        }                                                                       \
    }

__global__ __launch_bounds__(256) void mid_kernel(
    const float* __restrict__ x, const float* __restrict__ emb,
    const float* __restrict__ coef, const float2* __restrict__ V,
    const int* __restrict__ bins, unsigned short* __restrict__ Aimg)
{
    __shared__ unsigned short M1t[2][64 * 72];
    __shared__ unsigned short Yt[2][128 * 72];
    __shared__ float cosT[64];
    __shared__ float sinT[64];
    __shared__ float2 Vs2[19 * 32];   // rows 0 and 18 are zero halo
    __shared__ int Bns[17 * 32];
    __shared__ float xs[512];

    const int blk = blockIdx.x;
    const int b = blk >> 5, n = blk & 31;
    const int tid = threadIdx.x;
    const int wave = tid >> 6, lane = tid & 63, l15 = lane & 15, q = lane >> 4;
    const float C64 = 0.09817477042468103f;

    if (tid < 64) {
        float ang = (float)tid * C64;
        cosT[tid] = __cosf(ang);
        sinT[tid] = __sinf(ang);
    }
    {
        const float2* Vg = V + (size_t)blk * 544;
        const int* Bg = bins + (size_t)blk * 544;
        for (int i = tid; i < 544; i += 256) { Vs2[32 + i] = Vg[i]; Bns[i] = Bg[i]; }
        if (tid < 64) {
            int r = (tid < 32) ? tid : (18 * 32 + tid - 32);
            Vs2[r] = make_float2(0.f, 0.f);
        }
        for (int i = tid; i < 512; i += 256) xs[i] = x[(size_t)b * 16384 + i * 32 + n];
    }

    float win16[4][4];
    #pragma unroll
    for (int tt = 0; tt < 4; ++tt)
        #pragma unroll
        for (int i = 0; i < 4; ++i) {
            int t = tt * 16 + q * 4 + i;
            win16[tt][i] = 0.5f - 0.5f * __cosf((float)t * C64);
        }
    float renv[2][4];
    #pragma unroll
    for (int hf = 0; hf < 2; ++hf)
        #pragma unroll
        for (int i = 0; i < 4; ++i) {
            int k = hf * 16 + q * 4 + i;
            float w0 = 0.5f - 0.5f * __cosf((float)k * C64);
            float w1v = 0.5f - 0.5f * __cosf((float)(k + 32) * C64);
            renv[hf][i] = 1.0f / (w0 * w0 + w1v * w1v);
        }
    int ebase[2];
    float emb2[2];
    size_t cbase[2];
    const int mt = blk >> 7, mp = blk & 127, s = (mp >> 2) & 3;
    #pragma unroll
    for (int e2 = 0; e2 < 2; ++e2) {
        ebase[e2] = (wave * 2 + e2) * 16 + l15;
        emb2[e2] = emb[ebase[e2]];
        int e = ebase[e2];
        int echunk = e >> 5, clog = (e >> 3) & 3, cs = clog ^ s, el = e & 7;
        cbase[e2] = ((size_t)mt * 2048 + echunk) * 4096 + mp * 32 + cs * 8 + el;
    }

    float roll[2][4][4];
    #pragma unroll
    for (int e2 = 0; e2 < 2; ++e2)
        #pragma unroll
        for (int jj = 0; jj < 4; ++jj)
            #pragma unroll
            for (int i = 0; i < 4; ++i) roll[e2][jj][i] = 0.f;

    const int e1 = tid & 127;
    const int mg = (tid >> 7) << 4;
    const int tM = tid & 63;
    const int kg = wave << 4;

    __syncthreads();

    for (int w = 0; w < 17; ++w) {
        const int buf = w & 1;
        // ---- Y (bf16, packed cvt) -> Yt[buf] ----
        {
            const float4* cf = (const float4*)(coef + ((size_t)(w * 128 + e1)) * 8);
            float4 cA = cf[0];
            float4 cB = cf[1];
            unsigned int rep[8], imp[8];
            #pragma unroll
            for (int j2 = 0; j2 < 8; ++j2) {
                float rev[2], imv[2];
                #pragma unroll
                for (int sdx = 0; sdx < 2; ++sdx) {
                    int m = mg + j2 * 2 + sdx;
                    float2 vm = Vs2[(w + 1) * 32 + m];   // +1: zero-halo shift
                    float2 vl = Vs2[w * 32 + m];
                    float2 vp = Vs2[(w + 2) * 32 + m];
                    float re = cB.z;
                    re = fmaf(vm.x, cA.x, re); re = fmaf(-vm.y, cA.y, re);
                    re = fmaf(vl.x, cA.z, re); re = fmaf(-vl.y, cA.w, re);
                    re = fmaf(vp.x, cB.x, re); re = fmaf(-vp.y, cB.y, re);
                    float im = cB.w;
                    im = fmaf(vm.y, cA.x, im); im = fmaf(vm.x, cA.y, im);
                    im = fmaf(vl.y, cA.z, im); im = fmaf(vl.x, cA.w, im);
                    im = fmaf(vp.y, cB.x, im); im = fmaf(vp.x, cB.y, im);
                    rev[sdx] = fmaxf(re, 0.f);
                    imv[sdx] = fmaxf(im, 0.f);
                }
                rep[j2] = pkbf(rev[0], rev[1]);
                imp[j2] = pkbf(imv[0], imv[1]);
            }
            uint4* dr = (uint4*)&Yt[buf][e1 * 72 + mg];
            dr[0] = make_uint4(rep[0], rep[1], rep[2], rep[3]);
            dr[1] = make_uint4(rep[4], rep[5], rep[6], rep[7]);
            uint4* di = (uint4*)&Yt[buf][e1 * 72 + 32 + mg];
            di[0] = make_uint4(imp[0], imp[1], imp[2], imp[3]);
            di[1] = make_uint4(imp[4], imp[5], imp[6], imp[7]);
        }
        // ---- M1 basis (packed cvt) -> M1t[buf] ----
        {
            unsigned int mpk[8];
            #pragma unroll
            for (int j2 = 0; j2 < 8; ++j2) {
                float vv[2];
                #pragma unroll
                for (int sdx = 0; sdx < 2; ++sdx) {
                    int k = kg + j2 * 2 + sdx;
                    int m = k & 31;
                    int r = Bns[w * 32 + m];
                    float sc = (r == 0 || r == 32) ? 0.015625f : 0.03125f;
                    int idx = (r * tM) & 63;
                    vv[sdx] = (k < 32) ? (cosT[idx] * sc) : (-sinT[idx] * sc);
                }
                mpk[j2] = pkbf(vv[0], vv[1]);
            }
            uint4* dm = (uint4*)&M1t[buf][tM * 72 + kg];
            dm[0] = make_uint4(mpk[0], mpk[1], mpk[2], mpk[3]);
            dm[1] = make_uint4(mpk[4], mpk[5], mpk[6], mpk[7]);
        }
        __syncthreads();   // the only barrier this iteration

        v4f acc[4][2];
        #pragma unroll
        for (int tt = 0; tt < 4; ++tt)
            #pragma unroll
            for (int e2 = 0; e2 < 2; ++e2) acc[tt][e2] = (v4f){0.f, 0.f, 0.f, 0.f};
        #pragma unroll
        for (int ks = 0; ks < 2; ++ks) {
            v8s bfr[2];
            #pragma unroll
            for (int e2 = 0; e2 < 2; ++e2)
                bfr[e2] = *(const v8s*)&Yt[buf][ebase[e2] * 72 + ks * 32 + q * 8];
            #pragma unroll
            for (int tt = 0; tt < 4; ++tt) {
                v8s af = *(const v8s*)&M1t[buf][(tt * 16 + l15) * 72 + ks * 32 + q * 8];
                #pragma unroll
                for (int e2 = 0; e2 < 2; ++e2)
                    acc[tt][e2] = __builtin_amdgcn_mfma_f32_16x16x32_bf16(
                        af, bfr[e2], acc[tt][e2], 0, 0, 0);
            }
        }

        if ((w & 1) == 0) {
            MID_ROLL(0, 1, 2, 3);
            if (w > 0) {
                MID_FLUSH(0, 1);
            } else {
                // chunks 0,1 (abs samples [0,32)) are pad-trimmed: discard
                #pragma unroll
                for (int e2 = 0; e2 < 2; ++e2)
                    #pragma unroll
                    for (int i = 0; i < 4; ++i) {
                        roll[e2][0][i] = 0.f; roll[e2][1][i] = 0.f;
                    }
            }
        } else {
            MID_ROLL(2, 3, 0, 1);
            MID_FLUSH(2, 3);
        }
        // no trailing barrier: next iter writes buf^1; any wave writing buf^1
        // has passed barrier(w), which orders it after all iter-(w-1) reads.
    }
}

// ---------------------------------------------------------------------------
// Kernel D: FC1 split-K GEMM, 256x256 tile, 512 threads, BK=32.
// 3-stage DMA pipeline with counted vmcnt(4) + raw s_barrier. Flat grid 4*KS
// with XCD-pairing swizzle. Partials bf16, layout [row][ks][hid].
// ---------------------------------------------------------------------------
__global__ __launch_bounds__(512) void gemm_kernel(
    const unsigned short* __restrict__ Aimg, const unsigned short* __restrict__ w1p,
    unsigned short* __restrict__ hp, int iters, int KS)
{
    __shared__ unsigned short As[3][8192];
    __shared__ unsigned short Bs[3][8192];

    const int gid = blockIdx.x;
    const int xcd = gid & 7;
    const int u = gid >> 3;
    const int KS4 = KS >> 2;
    const int nt2 = (u >= KS4) ? 1 : 0;
    const int vv = u - nt2 * KS4;
    const int pid = vv * 8 + xcd;
    const int ks = pid >> 1;
    const int mt2 = pid & 1;

    const int tid = threadIdx.x;
    const int wave = tid >> 6, lane = tid & 63;
    const int l15 = lane & 15, q = lane >> 4;
    const int kb0 = ks * iters;

    const int isB = wave >> 2;
    const int sub = wave & 3;
    const unsigned short* gsrc = (isB
        ? w1p + ((size_t)(nt2 * 2 + (sub >> 1)) * 2048 + kb0) * 4096
        : Aimg + ((size_t)(mt2 * 2 + (sub >> 1)) * 2048 + kb0) * 4096)
        + (sub & 1) * 2048 + lane * 8;
    const int ldsoff = (sub >> 1) * 4096 + (sub & 1) * 2048;   // wave-uniform

    v4f acc[4][8];
    #pragma unroll
    for (int mf = 0; mf < 4; ++mf)
        #pragma unroll
        for (int nf = 0; nf < 8; ++nf) acc[mf][nf] = (v4f){0.f, 0.f, 0.f, 0.f};

    // prologue: stage 0 and 1
    {
        unsigned short* dst0 = (isB ? Bs[0] : As[0]) + ldsoff;
        #pragma unroll
        for (int j = 0; j < 4; ++j) async16(gsrc + j * 512, dst0 + j * 512);
        if (iters > 1) {
            const unsigned short* s1 = gsrc + 4096;
            unsigned short* dst1 = (isB ? Bs[1] : As[1]) + ldsoff;
            #pragma unroll
            for (int j = 0; j < 4; ++j) async16(s1 + j * 512, dst1 + j * 512);
        }
    }

    const int wm = wave >> 1, wn = wave & 1;
    const int ca = (q ^ ((l15 >> 2) & 3)) * 8;
    const int rA = (wm >> 1) * 4096 + ((wm & 1) * 64 + l15) * 32 + ca;
    const int rB = wn * 4096 + l15 * 32 + ca;

    for (int it = 0; it < iters; ++it) {
        // counted wait: oldest 4 (stage it) done; stage it+1 may stay in flight
        if (it + 1 < iters) {
            asm volatile("s_waitcnt vmcnt(4)" ::: "memory");
        } else {
            asm volatile("s_waitcnt vmcnt(0)" ::: "memory");
        }
        __builtin_amdgcn_s_barrier();
        __builtin_amdgcn_sched_barrier(0);
        if (it + 2 < iters) {
            const int nb = (it + 2) % 3;
            const unsigned short* src = gsrc + (size_t)(it + 2) * 4096;
            unsigned short* dst = (isB ? Bs[nb] : As[nb]) + ldsoff;
            #pragma unroll
            for (int j = 0; j < 4; ++j) async16(src + j * 512, dst + j * 512);
        }
        const int cur = it % 3;
        v8s af[4], bf[8];
        #pragma unroll
        for (int f = 0; f < 4; ++f) af[f] = *(const v8s*)&As[cur][rA + f * 512];
        #pragma unroll
        for (int nf = 0; nf < 8; ++nf) bf[nf] = *(const v8s*)&Bs[cur][rB + nf * 512];
        #pragma unroll
        for (int mf = 0; mf < 4; ++mf)
            #pragma unroll
            for (int nf = 0; nf < 8; ++nf)
                acc[mf][nf] = __builtin_amdgcn_mfma_f32_16x16x32_bf16(
                    af[mf], bf[nf], acc[mf][nf], 0, 0, 0);
    }

    #pragma unroll
    for (int mf = 0; mf < 4; ++mf)
        #pragma unroll
        for (int nf = 0; nf < 8; ++nf) {
            int row = mt2 * 256 + wm * 64 + mf * 16 + q * 4;
            int col = nt2 * 256 + wn * 128 + nf * 16 + l15;
            // transposed: hp[row][ks][hid] -> fc2 reads 64KB contiguous/row
            unsigned short* dst = hp + ((size_t)row * KS + ks) * 512 + col;
            #pragma unroll
            for (int i = 0; i < 4; ++i)
                dst[(size_t)i * KS * 512] = f2bf(acc[mf][nf][i]);
        }
}

// ---------------------------------------------------------------------------
// Kernel E (fused): per row — reduce bf16 split-K partials (contiguous 64KB)
// + b1 + leaky into LDS, then FC2 matvec (2-way split over h: 192 active
// threads, 256-long chains) + b2 -> out[b][p][n]. grid 512, 256 thr.
// ---------------------------------------------------------------------------
__global__ __launch_bounds__(256) void fc2_kernel(
    const unsigned short* __restrict__ hp, const float* __restrict__ b1,
    const float* __restrict__ w2, const float* __restrict__ b2,
    float* __restrict__ out, int KS)
{
    __shared__ float hbuf[512];
    __shared__ float part[2][96];
    const int row = blockIdx.x;
    const int tid = threadIdx.x;

    // thread t owns hids {2t, 2t+1}; hp row-major [row][ks][hid]
    const unsigned int* base = (const unsigned int*)(hp + (size_t)row * KS * 512) + tid;
    float a0 = 0.f, a1 = 0.f;
    #pragma unroll 8
    for (int k = 0; k < KS; ++k) {
        unsigned int v = base[k * 256];   // 512 ushort = 256 uint per slice
        a0 += bf2f((unsigned short)(v & 0xffff));
        a1 += bf2f((unsigned short)(v >> 16));
    }
    float s0 = a0 + b1[tid * 2];
    float s1 = a1 + b1[tid * 2 + 1];
    hbuf[tid * 2]     = (s0 > 0.f) ? s0 : 0.01f * s0;
    hbuf[tid * 2 + 1] = (s1 > 0.f) ? s1 : 0.01f * s1;
    __syncthreads();

    if (tid < 192) {
        const int c = (tid >= 96) ? 1 : 0;
        const int o = tid - 96 * c;
        float a = 0.f;
        #pragma unroll 8
        for (int h = c * 256; h < c * 256 + 256; ++h)
            a = fmaf(hbuf[h], w2[h * 96 + o], a);
        part[c][o] = a;
    }
    __syncthreads();

    if (tid < 96) {
        float a = part[0][tid] + part[1][tid] + b2[tid];
        int b = row >> 5, n = row & 31;
        out[(size_t)b * 3072 + tid * 32 + n] = a;
    }
}

// ---------------------------------------------------------------------------
extern "C" void kernel_launch(void* const* d_in, const int* in_sizes, int n_in,
                              void* d_out, int out_size, void* d_ws, size_t ws_size,
                              hipStream_t stream) {
    const float* x   = (const float*)d_in[0];
    const float* emb = (const float*)d_in[1];
    const float* Wr  = (const float*)d_in[2];
    const float* Wi  = (const float*)d_in[3];
    const float* Wrl = (const float*)d_in[4];
    const float* Wil = (const float*)d_in[5];
    const float* Wrr = (const float*)d_in[6];
    const float* Wir = (const float*)d_in[7];
    const float* br  = (const float*)d_in[8];
    const float* bi  = (const float*)d_in[9];
    const float* w1  = (const float*)d_in[10];
    const float* b1  = (const float*)d_in[11];
    const float* w2  = (const float*)d_in[12];
    const float* b2  = (const float*)d_in[13];

    char* ws = (char*)d_ws;
    float* coef          = (float*)(ws + OFF_COEF);
    float2* V            = (float2*)(ws + OFF_V);
    int* bins            = (int*)(ws + OFF_BINS);
    unsigned short* Aimg = (unsigned short*)(ws + OFF_AIMG);
    unsigned short* w1p  = (unsigned short*)(ws + OFF_W1P);
    unsigned short* hpp  = (unsigned short*)(ws + OFF_HP);

    int KS = 64;
    size_t hp_bytes = (size_t)KS * 512 * 512 * 2;
    if (OFF_HP + hp_bytes > ws_size) {
        KS = 32; hp_bytes = (size_t)KS * 512 * 512 * 2;
    }
    int iters = 2048 / KS;

    pre_kernel<<<dim3(1604), dim3(256), 0, stream>>>(
        w1, w1p, emb, Wr, Wi, Wrl, Wil, Wrr, Wir, br, bi, coef, x, V, bins);
    mid_kernel<<<dim3(512), dim3(256), 0, stream>>>(x, emb, coef, V, bins, Aimg);
    gemm_kernel<<<dim3(4 * KS), dim3(512), 0, stream>>>(Aimg, w1p, hpp, iters, KS);
    fc2_kernel<<<dim3(512), dim3(256), 0, stream>>>(hpp, b1, w2, b2, (float*)d_out, KS);
}

// Round 11
// 365.048 us; speedup vs baseline: 1.0438x; 1.0438x over previous
//
#include <hip/hip_runtime.h>
#include <hip/hip_bf16.h>

// B=16, SEQ=512, NF=32, E=128, HID=512, PRED=96, N_FFT=64, HOP=32, TOPM=32
// W=17, F=33, LAM=0.01
#define LAM 0.01f

typedef __attribute__((ext_vector_type(8))) short v8s;
typedef __attribute__((ext_vector_type(4))) float v4f;

static __device__ __forceinline__ unsigned short f2bf(float f) {
    union { float f; unsigned int u; } v; v.f = f;
    unsigned int u = v.u;
    u += 0x7fffu + ((u >> 16) & 1u);   // RNE
    return (unsigned short)(u >> 16);
}
static __device__ __forceinline__ float bf2f(unsigned short h) {
    union { unsigned int u; float f; } c; c.u = ((unsigned int)h) << 16;
    return c.f;
}
// packed 2xf32 -> 2xbf16 (v_cvt_pk_bf16_f32 on gfx950); lo=a, hi=b
static __device__ __forceinline__ unsigned int pkbf(float a, float b) {
    union { __hip_bfloat162 h; unsigned int u; } c;
    c.h = __float22bfloat162_rn(float2{a, b});
    return c.u;
}

// async global->LDS DMA, 16 B/lane; lds base wave-uniform, lane i -> base+16i
static __device__ __forceinline__ void async16(const void* g, void* l) {
    __builtin_amdgcn_global_load_lds(
        (const __attribute__((address_space(1))) unsigned int*)g,
        (__attribute__((address_space(3))) unsigned int*)l, 16, 0, 0);
}

// Workspace layout (bytes)
#define OFF_COEF 0ull
#define OFF_V    69632ull
#define OFF_BINS 2297856ull
#define OFF_AIMG 3411968ull                     // 512*65536 bf16 swizzled = 67,108,864
#define OFF_W1P  70520832ull                    // 65536*512 bf16 swizzled = 67,108,864
#define OFF_HP   137629696ull                   // KS*512*512*2 (bf16 partials)

// ---------------------------------------------------------------------------
// Kernel PRE — R8 verbatim (best measured: 79.6us / total 367.5).
//  bid <   68    : coef[w][e][j], 2 (w,j)-pairs/block.
//  bid <  1092   : stft for blk = bid-68 (w-split 2x, 1024 blocks).
//  else          : cvt w1 -> bf16 swizzled image via global_load_lds DMA
//                  with source-side group swizzle; shared 16 KB LDS.
// ---------------------------------------------------------------------------
__global__ __launch_bounds__(256) void pre_kernel(
    const float* __restrict__ w1, unsigned short* __restrict__ w1p,
    const float* __restrict__ emb,
    const float* __restrict__ Wr, const float* __restrict__ Wi,
    const float* __restrict__ Wrl, const float* __restrict__ Wil,
    const float* __restrict__ Wrr, const float* __restrict__ Wir,
    const float* __restrict__ br, const float* __restrict__ bi,
    float* __restrict__ coef,
    const float* __restrict__ x, float2* __restrict__ V, int* __restrict__ bins)
{
    __shared__ __align__(16) float smem[4096];   // 16 KB, shared by all branches

    const int tid = threadIdx.x;
    const int bid = blockIdx.x;

    if (bid < 68) {
        // ---- coef ----
        const int pair = bid * 2 + (tid >> 7);   // 0..135
        const int w = pair >> 3, j = pair & 7, e = tid & 127;
        float out;
        if (j < 6) {
            const float* Wj;
            switch (j) {
                case 0: Wj = Wr; break; case 1: Wj = Wi; break;
                case 2: Wj = Wrl; break; case 3: Wj = Wil; break;
                case 4: Wj = Wrr; break; default: Wj = Wir; break;
            }
            const float* p = Wj + (size_t)w * 16384 + e;
            float acc = 0.f;
            #pragma unroll 8
            for (int ep = 0; ep < 128; ++ep) acc = fmaf(emb[ep], p[ep * 128], acc);
            out = acc;
        } else if (j == 6) {
            out = br[w * 128 + e] - LAM;
        } else {
            out = bi[w * 128 + e] - LAM;
        }
        coef[((size_t)(w * 128 + e)) * 8 + j] = out;
        return;
    }

    if (bid < 1092) {
        // ---- stft (w-split 2x): blk in [0,1024); LDS carved from smem ----
        float* sigL  = smem;                    // 336 floats
        float* winT  = smem + 336;              // 64
        float2* tw   = (float2*)(smem + 400);   // 64 float2
        float2* Sbuf = (float2*)(smem + 528);   // 297 float2
        float* absb  = smem + 1122;             // 297

        const int blk = bid - 68;
        const int bn = blk >> 1, wh = blk & 1;
        const int b = bn >> 5, n = bn & 31;
        const int w0 = wh ? 9 : 0;
        const int nW = wh ? 8 : 9;
        const int sbase = wh ? 288 : 0;     // padded-signal offset of sigL[0]
        const int slen = wh ? 288 : 320;
        const float C64 = 0.09817477042468103f; // 2*pi/64

        if (tid < 64) {
            float ang = (float)tid * C64;
            winT[tid] = 0.5f - 0.5f * cosf(ang);
            tw[tid] = make_float2(cosf(ang), sinf(ang));   // libm: tie safety
        }
        for (int l = tid; l < slen; l += 256) {
            int g = sbase + l;
            int t = (g < 32) ? (32 - g) : ((g < 544) ? (g - 32) : (1054 - g)); // reflect
            sigL[l] = x[(size_t)b * 16384 + t * 32 + n];
        }
        __syncthreads();

        const int ntask = nW * 33;
        for (int task = tid; task < ntask; task += 256) {
            int wl = task / 33, f = task - wl * 33;
            float sr = 0.f, si = 0.f;
            int base = (w0 + wl) * 32 - sbase;
            for (int t = 0; t < 64; ++t) {
                float sw = sigL[base + t] * winT[t];
                float2 cs = tw[(f * t) & 63];
                sr = fmaf(sw, cs.x, sr);
                si = fmaf(sw, -cs.y, si);
            }
            Sbuf[task] = make_float2(sr, si);
            absb[task] = sqrtf(fmaf(sr, sr, si * si));
        }
        __syncthreads();

        for (int task = tid; task < ntask; task += 256) {
            int wl = task / 33, f = task - wl * 33;
            float a = absb[task];
            int base = wl * 33, rank = 0;
            for (int j = 0; j < 33; ++j) {
                float aj = absb[base + j];
                rank += (aj > a) || (aj == a && j < f);   // stable
            }
            if (rank < 32) {
                size_t o = ((size_t)bn * 17 + (w0 + wl)) * 32 + rank;
                V[o] = Sbuf[task];
                bins[o] = f;
            }
        }
        return;
    }

    // ---- cvt: w1 -> bf16 swizzled image; cb = bid-1092 in [0,8192) ----
    // DMA-staged: LDS slot (row r, group gl) holds w1 group (gl ^ 2*clog(r)).
    const int cb = bid - 1092;
    const int kb = cb & 2047, nt = cb >> 11;
    const int wv = tid >> 6, lane = tid & 63;

    #pragma unroll
    for (int j = 0; j < 4; ++j) {
        int r = wv * 8 + j * 2 + (lane >> 5);              // row this lane stages
        int g = (lane & 31) ^ (wv * 2);                    // swizzled source group
        const float* src = w1 + ((size_t)(kb * 32 + r)) * 512 + nt * 128 + g * 4;
        async16(src, (char*)smem + wv * 4096 + j * 1024);  // dest: base+lane*16
    }
    asm volatile("s_waitcnt vmcnt(0)" ::: "memory");
    __syncthreads();

    unsigned short* dst = w1p + ((size_t)nt * 2048 + kb) * 4096;
    #pragma unroll
    for (int p = 0; p < 2; ++p) {
        int pos = tid + 256 * p;            // 16-B chunk index
        int np = pos >> 2, cs = pos & 3;
        int clog = cs ^ ((np >> 2) & 3);
        int gsw = (((np >> 2) ^ (clog << 1)) << 2) + (np & 3);  // swizzled col
        unsigned int pk[4];
        #pragma unroll
        for (int j2 = 0; j2 < 4; ++j2) {
            int r0 = clog * 8 + j2 * 2;
            float a = smem[r0 * 128 + gsw];
            float b = smem[(r0 + 1) * 128 + gsw];
            pk[j2] = pkbf(a, b);
        }
        *(uint4*)&dst[pos * 8] = make_uint4(pk[0], pk[1], pk[2], pk[3]);
    }
}

// ---------------------------------------------------------------------------
// Kernel C: mid — verbatim R0 structure (best verified).
// Yt AND M1t double-buffered -> exactly ONE barrier per w-iteration.
// Zero-halo V table Vs2[19][32]. Per-(b,n) inputs in LDS; MFMA 64x128;
// register OLA; bf16 swizzled A-image write. grid 512, 256 thr.
// ---------------------------------------------------------------------------
#define MID_ROLL(J0, J1, J2, J3)                                                \
    {                                                                           \
        _Pragma("unroll") for (int e2 = 0; e2 < 2; ++e2)                        \
        _Pragma("unroll") for (int i = 0; i < 4; ++i) {                         \
            roll[e2][J0][i] = fmaf(acc[0][e2][i], win16[0][i], roll[e2][J0][i]);\
            roll[e2][J1][i] = fmaf(acc[1][e2][i], win16[1][i], roll[e2][J1][i]);\
            roll[e2][J2][i] = fmaf(acc[2][e2][i], win16[2][i], roll[e2][J2][i]);\
            roll[e2][J3][i] = fmaf(acc[3][e2][i], win16[3][i], roll[e2][J3][i]);\
        }                                                                       \
    }

#define MID_FLUSH(JJA, JJB)                                                     \
    {                                                                           \
        _Pragma("unroll") for (int i = 0; i < 4; ++i) {                         \
            int tp = 32 * (w - 1) + q * 4 + i;                                  \
            float xb = xs[tp];                                                  \
            _Pragma("unroll") for (int e2 = 0; e2 < 2; ++e2) {                  \
                float val = fmaf(roll[e2][JJA][i], renv[0][i], xb * emb2[e2]);  \
                Aimg[cbase[e2] + (size_t)tp * 16384] = f2bf(val);               \
                roll[e2][JJA][i] = 0.f;                                         \
            }                                                                   \
            int tp2 = tp + 16;                                                  \
            float xb2 = xs[tp2];                                                \
            _Pragma("unroll") for (int e2 = 0; e2 < 2; ++e2) {                  \
                float val = fmaf(roll[e2][JJB][i], renv[1][i], xb2 * emb2[e2]); \
                Aimg[cbase[e2] + (size_t)tp2 * 16384] = f2bf(val);              \
                roll[e2][JJB][i] = 0.f;                                         \
            }                                                                   \
        }                                                                       \
    }

__global__ __launch_bounds__(256) void mid_kernel(
    const float* __restrict__ x, const float* __restrict__ emb,
    const float* __restrict__ coef, const float2* __restrict__ V,
    const int* __restrict__ bins, unsigned short* __restrict__ Aimg)
{
    __shared__ unsigned short M1t[2][64 * 72];
    __shared__ unsigned short Yt[2][128 * 72];
    __shared__ float cosT[64];
    __shared__ float sinT[64];
    __shared__ float2 Vs2[19 * 32];   // rows 0 and 18 are zero halo
    __shared__ int Bns[17 * 32];
    __shared__ float xs[512];

    const int blk = blockIdx.x;
    const int b = blk >> 5, n = blk & 31;
    const int tid = threadIdx.x;
    const int wave = tid >> 6, lane = tid & 63, l15 = lane & 15, q = lane >> 4;
    const float C64 = 0.09817477042468103f;

    if (tid < 64) {
        float ang = (float)tid * C64;
        cosT[tid] = __cosf(ang);
        sinT[tid] = __sinf(ang);
    }
    {
        const float2* Vg = V + (size_t)blk * 544;
        const int* Bg = bins + (size_t)blk * 544;
        for (int i = tid; i < 544; i += 256) { Vs2[32 + i] = Vg[i]; Bns[i] = Bg[i]; }
        if (tid < 64) {
            int r = (tid < 32) ? tid : (18 * 32 + tid - 32);
            Vs2[r] = make_float2(0.f, 0.f);
        }
        for (int i = tid; i < 512; i += 256) xs[i] = x[(size_t)b * 16384 + i * 32 + n];
    }

    float win16[4][4];
    #pragma unroll
    for (int tt = 0; tt < 4; ++tt)
        #pragma unroll
        for (int i = 0; i < 4; ++i) {
            int t = tt * 16 + q * 4 + i;
            win16[tt][i] = 0.5f - 0.5f * __cosf((float)t * C64);
        }
    float renv[2][4];
    #pragma unroll
    for (int hf = 0; hf < 2; ++hf)
        #pragma unroll
        for (int i = 0; i < 4; ++i) {
            int k = hf * 16 + q * 4 + i;
            float w0 = 0.5f - 0.5f * __cosf((float)k * C64);
            float w1v = 0.5f - 0.5f * __cosf((float)(k + 32) * C64);
            renv[hf][i] = 1.0f / (w0 * w0 + w1v * w1v);
        }
    int ebase[2];
    float emb2[2];
    size_t cbase[2];
    const int mt = blk >> 7, mp = blk & 127, s = (mp >> 2) & 3;
    #pragma unroll
    for (int e2 = 0; e2 < 2; ++e2) {
        ebase[e2] = (wave * 2 + e2) * 16 + l15;
        emb2[e2] = emb[ebase[e2]];
        int e = ebase[e2];
        int echunk = e >> 5, clog = (e >> 3) & 3, cs = clog ^ s, el = e & 7;
        cbase[e2] = ((size_t)mt * 2048 + echunk) * 4096 + mp * 32 + cs * 8 + el;
    }

    float roll[2][4][4];
    #pragma unroll
    for (int e2 = 0; e2 < 2; ++e2)
        #pragma unroll
        for (int jj = 0; jj < 4; ++jj)
            #pragma unroll
            for (int i = 0; i < 4; ++i) roll[e2][jj][i] = 0.f;

    const int e1 = tid & 127;
    const int mg = (tid >> 7) << 4;
    const int tM = tid & 63;
    const int kg = wave << 4;

    __syncthreads();

    for (int w = 0; w < 17; ++w) {
        const int buf = w & 1;
        // ---- Y (bf16, packed cvt) -> Yt[buf] ----
        {
            const float4* cf = (const float4*)(coef + ((size_t)(w * 128 + e1)) * 8);
            float4 cA = cf[0];
            float4 cB = cf[1];
            unsigned int rep[8], imp[8];
            #pragma unroll
            for (int j2 = 0; j2 < 8; ++j2) {
                float rev[2], imv[2];
                #pragma unroll
                for (int sdx = 0; sdx < 2; ++sdx) {
                    int m = mg + j2 * 2 + sdx;
                    float2 vm = Vs2[(w + 1) * 32 + m];   // +1: zero-halo shift
                    float2 vl = Vs2[w * 32 + m];
                    float2 vp = Vs2[(w + 2) * 32 + m];
                    float re = cB.z;
                    re = fmaf(vm.x, cA.x, re); re = fmaf(-vm.y, cA.y, re);
                    re = fmaf(vl.x, cA.z, re); re = fmaf(-vl.y, cA.w, re);
                    re = fmaf(vp.x, cB.x, re); re = fmaf(-vp.y, cB.y, re);
                    float im = cB.w;
                    im = fmaf(vm.y, cA.x, im); im = fmaf(vm.x, cA.y, im);
                    im = fmaf(vl.y, cA.z, im); im = fmaf(vl.x, cA.w, im);
                    im = fmaf(vp.y, cB.x, im); im = fmaf(vp.x, cB.y, im);
                    rev[sdx] = fmaxf(re, 0.f);
                    imv[sdx] = fmaxf(im, 0.f);
                }
                rep[j2] = pkbf(rev[0], rev[1]);
                imp[j2] = pkbf(imv[0], imv[1]);
            }
            uint4* dr = (uint4*)&Yt[buf][e1 * 72 + mg];
            dr[0] = make_uint4(rep[0], rep[1], rep[2], rep[3]);
            dr[1] = make_uint4(rep[4], rep[5], rep[6], rep[7]);
            uint4* di = (uint4*)&Yt[buf][e1 * 72 + 32 + mg];
            di[0] = make_uint4(imp[0], imp[1], imp[2], imp[3]);
            di[1] = make_uint4(imp[4], imp[5], imp[6], imp[7]);
        }
        // ---- M1 basis (packed cvt) -> M1t[buf] ----
        {
            unsigned int mpk[8];
            #pragma unroll
            for (int j2 = 0; j2 < 8; ++j2) {
                float vv[2];
                #pragma unroll
                for (int sdx = 0; sdx < 2; ++sdx) {
                    int k = kg + j2 * 2 + sdx;
                    int m = k & 31;
                    int r = Bns[w * 32 + m];
                    float sc = (r == 0 || r == 32) ? 0.015625f : 0.03125f;
                    int idx = (r * tM) & 63;
                    vv[sdx] = (k < 32) ? (cosT[idx] * sc) : (-sinT[idx] * sc);
                }
                mpk[j2] = pkbf(vv[0], vv[1]);
            }
            uint4* dm = (uint4*)&M1t[buf][tM * 72 + kg];
            dm[0] = make_uint4(mpk[0], mpk[1], mpk[2], mpk[3]);
            dm[1] = make_uint4(mpk[4], mpk[5], mpk[6], mpk[7]);
        }
        __syncthreads();   // the only barrier this iteration

        v4f acc[4][2];
        #pragma unroll
        for (int tt = 0; tt < 4; ++tt)
            #pragma unroll
            for (int e2 = 0; e2 < 2; ++e2) acc[tt][e2] = (v4f){0.f, 0.f, 0.f, 0.f};
        #pragma unroll
        for (int ks = 0; ks < 2; ++ks) {
            v8s bfr[2];
            #pragma unroll
            for (int e2 = 0; e2 < 2; ++e2)
                bfr[e2] = *(const v8s*)&Yt[buf][ebase[e2] * 72 + ks * 32 + q * 8];
            #pragma unroll
            for (int tt = 0; tt < 4; ++tt) {
                v8s af = *(const v8s*)&M1t[buf][(tt * 16 + l15) * 72 + ks * 32 + q * 8];
                #pragma unroll
                for (int e2 = 0; e2 < 2; ++e2)
                    acc[tt][e2] = __builtin_amdgcn_mfma_f32_16x16x32_bf16(
                        af, bfr[e2], acc[tt][e2], 0, 0, 0);
            }
        }

        if ((w & 1) == 0) {
            MID_ROLL(0, 1, 2, 3);
            if (w > 0) {
                MID_FLUSH(0, 1);
            } else {
                // chunks 0,1 (abs samples [0,32)) are pad-trimmed: discard
                #pragma unroll
                for (int e2 = 0; e2 < 2; ++e2)
                    #pragma unroll
                    for (int i = 0; i < 4; ++i) {
                        roll[e2][0][i] = 0.f; roll[e2][1][i] = 0.f;
                    }
            }
        } else {
            MID_ROLL(2, 3, 0, 1);
            MID_FLUSH(2, 3);
        }
        // no trailing barrier: next iter writes buf^1; any wave writing buf^1
        // has passed barrier(w), which orders it after all iter-(w-1) reads.
    }
}

// ---------------------------------------------------------------------------
// Kernel D: FC1 split-K GEMM, 256x256 tile, 512 threads, BK=32.
// 3-stage DMA pipeline with counted vmcnt(4) + raw s_barrier.
// R11: XCD-QUAD swizzle — each ks's full 2x2 (mt2,nt2) quad lands on ONE XCD
// so the A-chunk (shared by nt2 pair) AND B-chunk (shared by mt2 pair) are
// fetched from HBM once and re-read from that XCD's L2. Old swizzle put the
// B-sharing pair on different XCDs -> 268 MB HBM reads (43us floor); new
// -> 134 MB (26us floor). Partials bf16, layout [row][ks][hid].
// ---------------------------------------------------------------------------
__global__ __launch_bounds__(512) void gemm_kernel(
    const unsigned short* __restrict__ Aimg, const unsigned short* __restrict__ w1p,
    unsigned short* __restrict__ hp, int iters, int KS)
{
    __shared__ unsigned short As[3][8192];
    __shared__ unsigned short Bs[3][8192];

    const int gid = blockIdx.x;
    const int xcd = gid & 7;          // CP round-robins consecutive blocks
    const int idx = gid >> 3;         // 0 .. KS/2-1
    const int ks = xcd * (KS >> 3) + (idx >> 2);   // 8 consecutive ks per XCD
    const int quad = idx & 3;
    const int mt2 = quad & 1;
    const int nt2 = quad >> 1;

    const int tid = threadIdx.x;
    const int wave = tid >> 6, lane = tid & 63;
    const int l15 = lane & 15, q = lane >> 4;
    const int kb0 = ks * iters;

    const int isB = wave >> 2;
    const int sub = wave & 3;
    const unsigned short* gsrc = (isB
        ? w1p + ((size_t)(nt2 * 2 + (sub >> 1)) * 2048 + kb0) * 4096
        : Aimg + ((size_t)(mt2 * 2 + (sub >> 1)) * 2048 + kb0) * 4096)
        + (sub & 1) * 2048 + lane * 8;
    const int ldsoff = (sub >> 1) * 4096 + (sub & 1) * 2048;   // wave-uniform

    v4f acc[4][8];
    #pragma unroll
    for (int mf = 0; mf < 4; ++mf)
        #pragma unroll
        for (int nf = 0; nf < 8; ++nf) acc[mf][nf] = (v4f){0.f, 0.f, 0.f, 0.f};

    // prologue: stage 0 and 1
    {
        unsigned short* dst0 = (isB ? Bs[0] : As[0]) + ldsoff;
        #pragma unroll
        for (int j = 0; j < 4; ++j) async16(gsrc + j * 512, dst0 + j * 512);
        if (iters > 1) {
            const unsigned short* s1 = gsrc + 4096;
            unsigned short* dst1 = (isB ? Bs[1] : As[1]) + ldsoff;
            #pragma unroll
            for (int j = 0; j < 4; ++j) async16(s1 + j * 512, dst1 + j * 512);
        }
    }

    const int wm = wave >> 1, wn = wave & 1;
    const int ca = (q ^ ((l15 >> 2) & 3)) * 8;
    const int rA = (wm >> 1) * 4096 + ((wm & 1) * 64 + l15) * 32 + ca;
    const int rB = wn * 4096 + l15 * 32 + ca;

    for (int it = 0; it < iters; ++it) {
        // counted wait: oldest 4 (stage it) done; stage it+1 may stay in flight
        if (it + 1 < iters) {
            asm volatile("s_waitcnt vmcnt(4)" ::: "memory");
        } else {
            asm volatile("s_waitcnt vmcnt(0)" ::: "memory");
        }
        __builtin_amdgcn_s_barrier();
        __builtin_amdgcn_sched_barrier(0);
        if (it + 2 < iters) {
            const int nb = (it + 2) % 3;
            const unsigned short* src = gsrc + (size_t)(it + 2) * 4096;
            unsigned short* dst = (isB ? Bs[nb] : As[nb]) + ldsoff;
            #pragma unroll
            for (int j = 0; j < 4; ++j) async16(src + j * 512, dst + j * 512);
        }
        const int cur = it % 3;
        v8s af[4], bf[8];
        #pragma unroll
        for (int f = 0; f < 4; ++f) af[f] = *(const v8s*)&As[cur][rA + f * 512];
        #pragma unroll
        for (int nf = 0; nf < 8; ++nf) bf[nf] = *(const v8s*)&Bs[cur][rB + nf * 512];
        #pragma unroll
        for (int mf = 0; mf < 4; ++mf)
            #pragma unroll
            for (int nf = 0; nf < 8; ++nf)
                acc[mf][nf] = __builtin_amdgcn_mfma_f32_16x16x32_bf16(
                    af[mf], bf[nf], acc[mf][nf], 0, 0, 0);
    }

    #pragma unroll
    for (int mf = 0; mf < 4; ++mf)
        #pragma unroll
        for (int nf = 0; nf < 8; ++nf) {
            int row = mt2 * 256 + wm * 64 + mf * 16 + q * 4;
            int col = nt2 * 256 + wn * 128 + nf * 16 + l15;
            // transposed: hp[row][ks][hid] -> fc2 reads 64KB contiguous/row
            unsigned short* dst = hp + ((size_t)row * KS + ks) * 512 + col;
            #pragma unroll
            for (int i = 0; i < 4; ++i)
                dst[(size_t)i * KS * 512] = f2bf(acc[mf][nf][i]);
        }
}

// ---------------------------------------------------------------------------
// Kernel E (fused): per row — reduce bf16 split-K partials (contiguous 64KB)
// + b1 + leaky into LDS, then FC2 matvec (2-way split over h: 192 active
// threads, 256-long chains) + b2 -> out[b][p][n]. grid 512, 256 thr.
// ---------------------------------------------------------------------------
__global__ __launch_bounds__(256) void fc2_kernel(
    const unsigned short* __restrict__ hp, const float* __restrict__ b1,
    const float* __restrict__ w2, const float* __restrict__ b2,
    float* __restrict__ out, int KS)
{
    __shared__ float hbuf[512];
    __shared__ float part[2][96];
    const int row = blockIdx.x;
    const int tid = threadIdx.x;

    // thread t owns hids {2t, 2t+1}; hp row-major [row][ks][hid]
    const unsigned int* base = (const unsigned int*)(hp + (size_t)row * KS * 512) + tid;
    float a0 = 0.f, a1 = 0.f;
    #pragma unroll 8
    for (int k = 0; k < KS; ++k) {
        unsigned int v = base[k * 256];   // 512 ushort = 256 uint per slice
        a0 += bf2f((unsigned short)(v & 0xffff));
        a1 += bf2f((unsigned short)(v >> 16));
    }
    float s0 = a0 + b1[tid * 2];
    float s1 = a1 + b1[tid * 2 + 1];
    hbuf[tid * 2]     = (s0 > 0.f) ? s0 : 0.01f * s0;
    hbuf[tid * 2 + 1] = (s1 > 0.f) ? s1 : 0.01f * s1;
    __syncthreads();

    if (tid < 192) {
        const int c = (tid >= 96) ? 1 : 0;
        const int o = tid - 96 * c;
        float a = 0.f;
        #pragma unroll 8
        for (int h = c * 256; h < c * 256 + 256; ++h)
            a = fmaf(hbuf[h], w2[h * 96 + o], a);
        part[c][o] = a;
    }
    __syncthreads();

    if (tid < 96) {
        float a = part[0][tid] + part[1][tid] + b2[tid];
        int b = row >> 5, n = row & 31;
        out[(size_t)b * 3072 + tid * 32 + n] = a;
    }
}

// ---------------------------------------------------------------------------
extern "C" void kernel_launch(void* const* d_in, const int* in_sizes, int n_in,
                              void* d_out, int out_size, void* d_ws, size_t ws_size,
                              hipStream_t stream) {
    const float* x   = (const float*)d_in[0];
    const float* emb = (const float*)d_in[1];
    const float* Wr  = (const float*)d_in[2];
    const float* Wi  = (const float*)d_in[3];
    const float* Wrl = (const float*)d_in[4];
    const float* Wil = (const float*)d_in[5];
    const float* Wrr = (const float*)d_in[6];
    const float* Wir = (const float*)d_in[7];
    const float* br  = (const float*)d_in[8];
    const float* bi  = (const float*)d_in[9];
    const float* w1  = (const float*)d_in[10];
    const float* b1  = (const float*)d_in[11];
    const float* w2  = (const float*)d_in[12];
    const float* b2  = (const float*)d_in[13];

    char* ws = (char*)d_ws;
    float* coef          = (float*)(ws + OFF_COEF);
    float2* V            = (float2*)(ws + OFF_V);
    int* bins            = (int*)(ws + OFF_BINS);
    unsigned short* Aimg = (unsigned short*)(ws + OFF_AIMG);
    unsigned short* w1p  = (unsigned short*)(ws + OFF_W1P);
    unsigned short* hpp  = (unsigned short*)(ws + OFF_HP);

    int KS = 64;
    size_t hp_bytes = (size_t)KS * 512 * 512 * 2;
    if (OFF_HP + hp_bytes > ws_size) {
        KS = 32; hp_bytes = (size_t)KS * 512 * 512 * 2;
    }
    int iters = 2048 / KS;

    pre_kernel<<<dim3(9284), dim3(256), 0, stream>>>(
        w1, w1p, emb, Wr, Wi, Wrl, Wil, Wrr, Wir, br, bi, coef, x, V, bins);
    mid_kernel<<<dim3(512), dim3(256), 0, stream>>>(x, emb, coef, V, bins, Aimg);
    gemm_kernel<<<dim3(4 * KS), dim3(512), 0, stream>>>(Aimg, w1p, hpp, iters, KS);
    fc2_kernel<<<dim3(512), dim3(256), 0, stream>>>(hpp, b1, w2, b2, (float*)d_out, KS);
}